// Round 16
// baseline (197.004 us; speedup 1.0000x reference)
//
#include <hip/hip_runtime.h>
#include <hip/hip_bf16.h>
#include <math.h>

constexpr int N = 16384, D = 256, C = 10000;
constexpr float S = 30.0f, MARGIN = 0.4f;
constexpr int BM = 256, BN = 128;
constexpr int CP = ((C + BN - 1) / BN) * BN; // 10112
constexpr int NX = N / BM;                   // 64 row tiles
constexpr int NY = CP / BN;                  // 79 col tiles
constexpr int NWG = NX * NY;                 // 5056 = 8 * 8 * 79
constexpr float S_LOG2E = 43.2808512266689f; // S * log2(e)

constexpr int PREPX_BLOCKS = N / 16;          // 1024 (16-row groups, frag pack)
constexpr int PREPW_BLOCKS = (CP * D) / 1024; // 2528 (plain bf16 rows, padded)

using bf16 = __hip_bfloat16;
typedef __attribute__((ext_vector_type(8))) short short8;
typedef __attribute__((ext_vector_type(4))) short short4v;
typedef __attribute__((ext_vector_type(4))) float f32x4;

#define DRAIN_DMA()                                        \
    do {                                                   \
        asm volatile("s_waitcnt vmcnt(0)" ::: "memory");   \
        __builtin_amdgcn_sched_barrier(0);                 \
    } while (0)

__device__ inline short8 pack8(f32x4 a, f32x4 b, float sc) {
    short8 s;
    s[0] = (short)__bfloat16_as_ushort(__float2bfloat16(a.x * sc));
    s[1] = (short)__bfloat16_as_ushort(__float2bfloat16(a.y * sc));
    s[2] = (short)__bfloat16_as_ushort(__float2bfloat16(a.z * sc));
    s[3] = (short)__bfloat16_as_ushort(__float2bfloat16(a.w * sc));
    s[4] = (short)__bfloat16_as_ushort(__float2bfloat16(b.x * sc));
    s[5] = (short)__bfloat16_as_ushort(__float2bfloat16(b.y * sc));
    s[6] = (short)__bfloat16_as_ushort(__float2bfloat16(b.z * sc));
    s[7] = (short)__bfloat16_as_ushort(__float2bfloat16(b.w * sc));
    return s;
}

// ---------------- fused prep ----------------
// x: normalize + pre-scale by S*log2e, packed into 16x16x32 A-fragment order
//    (R9-verified). tgt in f32.
// W: plain row-major bf16, rows [C, CP) zero-padded — staged into LDS by the
//    GEMM via global_load_lds.
__global__ __launch_bounds__(256) void prep(const float* __restrict__ x,
                                            const int* __restrict__ labels,
                                            const float* __restrict__ W,
                                            bf16* __restrict__ Af,
                                            float* __restrict__ tgt,
                                            bf16* __restrict__ Wb,
                                            float* __restrict__ out) {
    const int bid = blockIdx.x;
    if (bid == 0 && threadIdx.x == 0) out[0] = 0.0f;

    if (bid < PREPX_BLOCKS) {
        const int tl = threadIdx.x;
        const int r = tl >> 4, c = tl & 15;
        const int rg = bid;
        const int row = rg * 16 + r;
        const float* xr = x + (size_t)row * D + c * 16;
        f32x4 v0 = *(const f32x4*)(xr + 0);
        f32x4 v1 = *(const f32x4*)(xr + 4);
        f32x4 v2 = *(const f32x4*)(xr + 8);
        f32x4 v3 = *(const f32x4*)(xr + 12);

        float ssq = v0.x*v0.x + v0.y*v0.y + v0.z*v0.z + v0.w*v0.w
                  + v1.x*v1.x + v1.y*v1.y + v1.z*v1.z + v1.w*v1.w
                  + v2.x*v2.x + v2.y*v2.y + v2.z*v2.z + v2.w*v2.w
                  + v3.x*v3.x + v3.y*v3.y + v3.z*v3.z + v3.w*v3.w;
        ssq += __shfl_xor(ssq, 1);
        ssq += __shfl_xor(ssq, 2);
        ssq += __shfl_xor(ssq, 4);
        ssq += __shfl_xor(ssq, 8);
        float rinv = rsqrtf(ssq);

        const int lab = labels[row];
        const float* wr = W + (size_t)lab * D + c * 16;
        f32x4 w0 = *(const f32x4*)(wr + 0);
        f32x4 w1 = *(const f32x4*)(wr + 4);
        f32x4 w2 = *(const f32x4*)(wr + 8);
        f32x4 w3 = *(const f32x4*)(wr + 12);
        float td = v0.x*w0.x + v0.y*w0.y + v0.z*w0.z + v0.w*w0.w
                 + v1.x*w1.x + v1.y*w1.y + v1.z*w1.z + v1.w*w1.w
                 + v2.x*w2.x + v2.y*w2.y + v2.z*w2.z + v2.w*w2.w
                 + v3.x*w3.x + v3.y*w3.y + v3.z*w3.z + v3.w*w3.w;
        td += __shfl_xor(td, 1);
        td += __shfl_xor(td, 2);
        td += __shfl_xor(td, 4);
        td += __shfl_xor(td, 8);
        if (c == 0) tgt[row] = td * rinv;

        const float sc = rinv * S_LOG2E;
        const size_t fb = ((size_t)rg * 8 + (c >> 1)) * 512;   // frag (rg, kk=c>>1)
        const int kq0 = (c & 1) * 2;
        *(short8*)(Af + fb + (size_t)(kq0 * 16 + r) * 8)       = pack8(v0, v1, sc);
        *(short8*)(Af + fb + (size_t)((kq0 + 1) * 16 + r) * 8) = pack8(v2, v3, sc);
    } else {
        // plain row-major W -> bf16, zero-pad rows [C, CP)
        int i = ((bid - PREPX_BLOCKS) * 256 + threadIdx.x) * 4;
        int r = i >> 8;                                  // D == 256
        short4v sv;
        if (r < C) {
            f32x4 v = *(const f32x4*)(W + i);
            sv.x = (short)__bfloat16_as_ushort(__float2bfloat16(v.x));
            sv.y = (short)__bfloat16_as_ushort(__float2bfloat16(v.y));
            sv.z = (short)__bfloat16_as_ushort(__float2bfloat16(v.z));
            sv.w = (short)__bfloat16_as_ushort(__float2bfloat16(v.w));
        } else {
            sv = short4v{0, 0, 0, 0};
        }
        *(short4v*)(Wb + i) = sv;
    }
}

// ---------------- main GEMM + exp2 + per-tile row partials ----------------
// R13 structure with 32 KB LDS: B panel staged in TWO K-halves [128][128]
// into one buffer (one extra barrier pair). blocks/CU = min(LDS 160/32=5,
// VGPR 2048/512=4) = 4 -> 16 waves/CU, 2x R13. A frag-direct from L2 with
// 1-deep ping-pong; K-loop barrier-free within each half. Per-wave 64x128.
__global__ __launch_bounds__(256) void gemm_exp(const bf16* __restrict__ Af,
                                                const bf16* __restrict__ Wb,
                                                float* __restrict__ partial) { // [NY][N]
    __shared__ __align__(16) bf16 Bs[BN * 128];   // 32 KB: [col][k-half], swizzled

    // ---- XCD-aware decode (bijective: NWG = 8 * 8 * 79) ----
    const int bid = blockIdx.x;
    const int xcd = bid & 7;
    const int idx = bid >> 3;          // 0..631
    const int xl  = idx & 7;           // x within XCD chunk (fast)
    const int y   = idx >> 3;          // 0..78 (slow)
    const int tile_r = (xcd * 8 + xl) * BM;
    const int tile_c = y * BN;

    const int t = threadIdx.x;
    const int lane = t & 63, w = t >> 6;   // wave w owns rows w*64..+64, all 128 cols

    // stage geometry: 32 chunks of 1 KB = 4 rows x 256 B; lane l covers
    // row c*4 + (l>>4), granule (l&15) of 16 per row. XOR-swizzle by row&7.
    auto STAGE = [&](int h) {              // h = K-half (0: k<128, 1: k>=128)
        #pragma unroll
        for (int q = 0; q < 8; ++q) {
            int c = w * 8 + q;                        // chunk 0..31, wave-uniform
            int row = c * 4 + (lane >> 4);            // B-panel row (class col) 0..127
            int srcg = (lane & 15) ^ (row & 7);       // pre-swizzled source granule
            const bf16* gb = Wb + (size_t)(tile_c + row) * D + h * 128 + srcg * 8;
            __builtin_amdgcn_global_load_lds(
                (const __attribute__((address_space(1))) void*)gb,
                (__attribute__((address_space(3))) void*)(Bs + c * 512),
                16, 0, 0);
        }
    };

    // ---- A fragment pointers (frag-order buffer, contiguous 1KB per frag) ----
    const bf16* ap[4];
    #pragma unroll
    for (int m = 0; m < 4; ++m)
        ap[m] = Af + ((size_t)((tile_r >> 4) + w * 4 + m) * 8) * 512 + lane * 8;

    f32x4 acc[4][8] = {};
    short8 a[2][4];

    const int g0 = lane >> 4;       // k-quad within fragment
    const int x7 = lane & 7;        // swizzle key (row&7 == lane&7 for frag rows)

    STAGE(0);
    #pragma unroll
    for (int m = 0; m < 4; ++m) a[0][m] = *(const short8*)(ap[m]);  // A kg=0, overlaps stage
    DRAIN_DMA();
    __syncthreads();   // B half0 visible

    #pragma unroll
    for (int h = 0; h < 2; ++h) {
        #pragma unroll
        for (int kk = 0; kk < 4; ++kk) {          // fully unrolled -> static indices
            const int kg = h * 4 + kk;            // global k-step 0..7
            const int cur = kg & 1, nxt = cur ^ 1;
            if (kg < 7) {
                #pragma unroll
                for (int m = 0; m < 4; ++m)
                    a[nxt][m] = *(const short8*)(ap[m] + (kg + 1) * 512);
            }
            short8 bf[8];
            #pragma unroll
            for (int n = 0; n < 8; ++n) {
                int row = n * 16 + (lane & 15);             // B-panel row (class col)
                int g = (kk * 4 + g0) ^ x7;                 // swizzled k-granule (0..15)
                bf[n] = *(const short8*)(Bs + row * 128 + g * 8);
            }
            #pragma unroll
            for (int m = 0; m < 4; ++m)
                #pragma unroll
                for (int n = 0; n < 8; ++n)
                    acc[m][n] = __builtin_amdgcn_mfma_f32_16x16x32_bf16(a[cur][m], bf[n], acc[m][n], 0, 0, 0);
        }
        if (h == 0) {
            __syncthreads();   // all waves done reading half0
            STAGE(1);
            DRAIN_DMA();
            __syncthreads();   // B half1 visible
        }
    }

    __syncthreads();   // K-loop reads of Bs done; reuse as epilogue scratch
    float* eps = (float*)Bs;   // 256 floats

    // ---- epilogue: exp2(acc), mask padded cols, row sums (rows unique per wave) ----
    #pragma unroll
    for (int m = 0; m < 4; ++m) {
        float rs[4] = {0.f, 0.f, 0.f, 0.f};
        #pragma unroll
        for (int n = 0; n < 8; ++n) {
            int gcol = tile_c + n * 16 + (lane & 15);
            bool ok = (gcol < C);
            #pragma unroll
            for (int r = 0; r < 4; ++r) {
                float e = ok ? __builtin_amdgcn_exp2f(acc[m][n][r]) : 0.0f;
                rs[r] += e;
            }
        }
        #pragma unroll
        for (int r = 0; r < 4; ++r) {
            float v = rs[r];
            v += __shfl_xor(v, 1);
            v += __shfl_xor(v, 2);
            v += __shfl_xor(v, 4);
            v += __shfl_xor(v, 8);
            if ((lane & 15) == 0)
                eps[w * 64 + m * 16 + (lane >> 4) * 4 + r] = v;
        }
    }
    __syncthreads();
    partial[(size_t)y * N + tile_r + t] = eps[t];   // coalesced 256-float store
}

// ---------------- loss: reduce partials + per-row loss + single atomic per block ----------------
__global__ __launch_bounds__(256) void loss_part(const float* __restrict__ tgt,
                                                 const float* __restrict__ partial,
                                                 float* __restrict__ out) {
    int i = blockIdx.x * 256 + threadIdx.x;   // row
    float sum = 0.0f;
    #pragma unroll 1
    for (int y = 0; y < NY; ++y) sum += partial[(size_t)y * N + i];  // coalesced per y

    float tg = tgt[i];
    float num = S * (tg - MARGIN);
    float den = __expf(num) + sum - __expf(S * tg);
    float L = num - logf(den);

    float v = L;
    #pragma unroll
    for (int off = 1; off < 64; off <<= 1) v += __shfl_xor(v, off);
    __shared__ float s4[4];
    int lane = threadIdx.x & 63, w = threadIdx.x >> 6;
    if (lane == 0) s4[w] = v;
    __syncthreads();
    if (threadIdx.x == 0) {
        float bsum = s4[0] + s4[1] + s4[2] + s4[3];
        atomicAdd(out, -bsum / (float)N);
    }
}

// ---------------- launch ----------------
extern "C" void kernel_launch(void* const* d_in, const int* in_sizes, int n_in,
                              void* d_out, int out_size, void* d_ws, size_t ws_size,
                              hipStream_t stream) {
    const float* x = (const float*)d_in[0];
    const int* labels = (const int*)d_in[1];
    const float* W = (const float*)d_in[2];

    char* ws = (char*)d_ws;
    bf16* Af       = (bf16*)(ws);                    // N*D*2 (frag order)   =  8,388,608
    bf16* Wb       = (bf16*)(ws + 8388608);          // CP*D*2 (row-major)   =  5,177,344
    float* tgt     = (float*)(ws + 13565952);        // N*4                  =     65,536
    float* partial = (float*)(ws + 13631488);        // NY*N*4               =  5,177,344
    float* out = (float*)d_out;

    prep<<<PREPX_BLOCKS + PREPW_BLOCKS, 256, 0, stream>>>(x, labels, W, Af, tgt, Wb, out);
    gemm_exp<<<NWG, 256, 0, stream>>>(Af, Wb, partial);
    loss_part<<<N / 256, 256, 0, stream>>>(tgt, partial, out);
}

// Round 17
// 185.774 us; speedup vs baseline: 1.0604x; 1.0604x over previous
//
#include <hip/hip_runtime.h>
#include <hip/hip_bf16.h>
#include <math.h>

constexpr int N = 16384, D = 256, C = 10000;
constexpr float S = 30.0f, MARGIN = 0.4f;
constexpr int BM = 256, BN = 128;
constexpr int CP = ((C + BN - 1) / BN) * BN; // 10112
constexpr int NX = N / BM;                   // 64 row tiles
constexpr int NY = CP / BN;                  // 79 col tiles
constexpr int NWG = NX * NY;                 // 5056 = 8 * 8 * 79
constexpr float S_LOG2E = 43.2808512266689f; // S * log2(e)

constexpr int PREPX_BLOCKS = N / 16;          // 1024 (16-row groups, frag pack)
constexpr int PREPW_BLOCKS = (CP * D) / 1024; // 2528 (plain bf16 rows, padded)

using bf16 = __hip_bfloat16;
typedef __attribute__((ext_vector_type(8))) short short8;
typedef __attribute__((ext_vector_type(4))) short short4v;
typedef __attribute__((ext_vector_type(4))) float f32x4;

#define DRAIN_DMA()                                        \
    do {                                                   \
        asm volatile("s_waitcnt vmcnt(0)" ::: "memory");   \
        __builtin_amdgcn_sched_barrier(0);                 \
    } while (0)

__device__ inline short8 pack8(f32x4 a, f32x4 b, float sc) {
    short8 s;
    s[0] = (short)__bfloat16_as_ushort(__float2bfloat16(a.x * sc));
    s[1] = (short)__bfloat16_as_ushort(__float2bfloat16(a.y * sc));
    s[2] = (short)__bfloat16_as_ushort(__float2bfloat16(a.z * sc));
    s[3] = (short)__bfloat16_as_ushort(__float2bfloat16(a.w * sc));
    s[4] = (short)__bfloat16_as_ushort(__float2bfloat16(b.x * sc));
    s[5] = (short)__bfloat16_as_ushort(__float2bfloat16(b.y * sc));
    s[6] = (short)__bfloat16_as_ushort(__float2bfloat16(b.z * sc));
    s[7] = (short)__bfloat16_as_ushort(__float2bfloat16(b.w * sc));
    return s;
}

// ---------------- fused prep ----------------
// x: normalize + pre-scale by S*log2e, packed into 16x16x32 A-fragment order
//    (R9-verified). tgt in f32.
// W: plain row-major bf16, rows [C, CP) zero-padded — staged into LDS by the
//    GEMM via global_load_lds.
__global__ __launch_bounds__(256) void prep(const float* __restrict__ x,
                                            const int* __restrict__ labels,
                                            const float* __restrict__ W,
                                            bf16* __restrict__ Af,
                                            float* __restrict__ tgt,
                                            bf16* __restrict__ Wb,
                                            float* __restrict__ out) {
    const int bid = blockIdx.x;
    if (bid == 0 && threadIdx.x == 0) out[0] = 0.0f;

    if (bid < PREPX_BLOCKS) {
        const int tl = threadIdx.x;
        const int r = tl >> 4, c = tl & 15;
        const int rg = bid;
        const int row = rg * 16 + r;
        const float* xr = x + (size_t)row * D + c * 16;
        f32x4 v0 = *(const f32x4*)(xr + 0);
        f32x4 v1 = *(const f32x4*)(xr + 4);
        f32x4 v2 = *(const f32x4*)(xr + 8);
        f32x4 v3 = *(const f32x4*)(xr + 12);

        float ssq = v0.x*v0.x + v0.y*v0.y + v0.z*v0.z + v0.w*v0.w
                  + v1.x*v1.x + v1.y*v1.y + v1.z*v1.z + v1.w*v1.w
                  + v2.x*v2.x + v2.y*v2.y + v2.z*v2.z + v2.w*v2.w
                  + v3.x*v3.x + v3.y*v3.y + v3.z*v3.z + v3.w*v3.w;
        ssq += __shfl_xor(ssq, 1);
        ssq += __shfl_xor(ssq, 2);
        ssq += __shfl_xor(ssq, 4);
        ssq += __shfl_xor(ssq, 8);
        float rinv = rsqrtf(ssq);

        const int lab = labels[row];
        const float* wr = W + (size_t)lab * D + c * 16;
        f32x4 w0 = *(const f32x4*)(wr + 0);
        f32x4 w1 = *(const f32x4*)(wr + 4);
        f32x4 w2 = *(const f32x4*)(wr + 8);
        f32x4 w3 = *(const f32x4*)(wr + 12);
        float td = v0.x*w0.x + v0.y*w0.y + v0.z*w0.z + v0.w*w0.w
                 + v1.x*w1.x + v1.y*w1.y + v1.z*w1.z + v1.w*w1.w
                 + v2.x*w2.x + v2.y*w2.y + v2.z*w2.z + v2.w*w2.w
                 + v3.x*w3.x + v3.y*w3.y + v3.z*w3.z + v3.w*w3.w;
        td += __shfl_xor(td, 1);
        td += __shfl_xor(td, 2);
        td += __shfl_xor(td, 4);
        td += __shfl_xor(td, 8);
        if (c == 0) tgt[row] = td * rinv;

        const float sc = rinv * S_LOG2E;
        const size_t fb = ((size_t)rg * 8 + (c >> 1)) * 512;   // frag (rg, kk=c>>1)
        const int kq0 = (c & 1) * 2;
        *(short8*)(Af + fb + (size_t)(kq0 * 16 + r) * 8)       = pack8(v0, v1, sc);
        *(short8*)(Af + fb + (size_t)((kq0 + 1) * 16 + r) * 8) = pack8(v2, v3, sc);
    } else {
        // plain row-major W -> bf16, zero-pad rows [C, CP)
        int i = ((bid - PREPX_BLOCKS) * 256 + threadIdx.x) * 4;
        int r = i >> 8;                                  // D == 256
        short4v sv;
        if (r < C) {
            f32x4 v = *(const f32x4*)(W + i);
            sv.x = (short)__bfloat16_as_ushort(__float2bfloat16(v.x));
            sv.y = (short)__bfloat16_as_ushort(__float2bfloat16(v.y));
            sv.z = (short)__bfloat16_as_ushort(__float2bfloat16(v.z));
            sv.w = (short)__bfloat16_as_ushort(__float2bfloat16(v.w));
        } else {
            sv = short4v{0, 0, 0, 0};
        }
        *(short4v*)(Wb + i) = sv;
    }
}

// ---------------- main GEMM + exp2 + per-tile row partials ----------------
// R13 structure (verified 105 us) + two additive changes:
//  (1) A prefetch deepened to 2 steps: the load for step kk+2 is issued AFTER
//      the MFMA cluster of step kk (2-slot reuse, zero extra registers; HW
//      WAR scoreboard orders the load write after the MFMA operand reads).
//  (2) s_setprio(1) around the MFMA cluster (T5; waves here are independent,
//      not barrier-lockstep, the regime where setprio measured +4-7%).
// B panel [128][256] staged ONCE into 64 KB LDS (XOR-swizzled), A frag-direct
// from L2. Barrier-free K-loop. 2 blocks/CU x 4 waves. Per-wave tile 64x128.
__global__ __launch_bounds__(256) void gemm_exp(const bf16* __restrict__ Af,
                                                const bf16* __restrict__ Wb,
                                                float* __restrict__ partial) { // [NY][N]
    __shared__ __align__(16) bf16 Bs[BN * D];   // 64 KB: [col][k], granule-swizzled

    // ---- XCD-aware decode (bijective: NWG = 8 * 8 * 79) ----
    const int bid = blockIdx.x;
    const int xcd = bid & 7;
    const int idx = bid >> 3;          // 0..631
    const int xl  = idx & 7;           // x within XCD chunk (fast)
    const int y   = idx >> 3;          // 0..78 (slow)
    const int tile_r = (xcd * 8 + xl) * BM;
    const int tile_c = y * BN;

    const int t = threadIdx.x;
    const int lane = t & 63, w = t >> 6;   // wave w owns rows w*64..+64, all 128 cols

    // ---- prologue: stage B panel (64 chunks of 1KB = 2 rows x 512B) ----
    #pragma unroll
    for (int q = 0; q < 16; ++q) {
        int c = w * 16 + q;                       // chunk 0..63, wave-uniform
        int row = 2 * c + (lane >> 5);            // B-panel row (= class col) 0..127
        int srcg = (lane & 31) ^ (row & 7);       // pre-swizzled source granule
        const bf16* gb = Wb + (size_t)(tile_c + row) * D + srcg * 8;
        __builtin_amdgcn_global_load_lds(
            (const __attribute__((address_space(1))) void*)gb,
            (__attribute__((address_space(3))) void*)(Bs + c * 512),
            16, 0, 0);
    }

    // ---- A fragment pointers (frag-order buffer, contiguous 1KB per frag) ----
    const bf16* ap[4];
    #pragma unroll
    for (int m = 0; m < 4; ++m)
        ap[m] = Af + ((size_t)((tile_r >> 4) + w * 4 + m) * 8) * 512 + lane * 8;

    f32x4 acc[4][8] = {};
    short8 a[2][4];
    // preload A for steps 0 and 1 (2-deep from the start)
    #pragma unroll
    for (int m = 0; m < 4; ++m) a[0][m] = *(const short8*)(ap[m]);
    #pragma unroll
    for (int m = 0; m < 4; ++m) a[1][m] = *(const short8*)(ap[m] + 512);

    DRAIN_DMA();
    __syncthreads();   // B panel fully visible; the ONLY K-path barrier

    const int g0 = lane >> 4;       // k-quad within fragment
    const int x7 = lane & 7;        // swizzle key (row&7 == lane&7 for frag rows)

    #pragma unroll
    for (int kk = 0; kk < 8; ++kk) {           // fully unrolled -> static indices
        const int cur = kk & 1;
        short8 bf[8];
        #pragma unroll
        for (int n = 0; n < 8; ++n) {
            int row = n * 16 + (lane & 15);                 // B-panel row (class col)
            int g = (kk * 4 + g0) ^ x7;                     // swizzled k-granule
            bf[n] = *(const short8*)(Bs + row * 256 + g * 8);
        }
        __builtin_amdgcn_s_setprio(1);
        #pragma unroll
        for (int m = 0; m < 4; ++m)
            #pragma unroll
            for (int n = 0; n < 8; ++n)
                acc[m][n] = __builtin_amdgcn_mfma_f32_16x16x32_bf16(a[cur][m], bf[n], acc[m][n], 0, 0, 0);
        __builtin_amdgcn_s_setprio(0);
        if (kk < 6) {
            // slot `cur` fully consumed by this step's MFMAs -> load step kk+2
            #pragma unroll
            for (int m = 0; m < 4; ++m)
                a[cur][m] = *(const short8*)(ap[m] + (kk + 2) * 512);
        }
    }

    __syncthreads();   // K-loop reads of Bs done; reuse as epilogue scratch
    float* eps = (float*)Bs;   // 256 floats

    // ---- epilogue: exp2(acc), mask padded cols, row sums (rows unique per wave) ----
    #pragma unroll
    for (int m = 0; m < 4; ++m) {
        float rs[4] = {0.f, 0.f, 0.f, 0.f};
        #pragma unroll
        for (int n = 0; n < 8; ++n) {
            int gcol = tile_c + n * 16 + (lane & 15);
            bool ok = (gcol < C);
            #pragma unroll
            for (int r = 0; r < 4; ++r) {
                float e = ok ? __builtin_amdgcn_exp2f(acc[m][n][r]) : 0.0f;
                rs[r] += e;
            }
        }
        #pragma unroll
        for (int r = 0; r < 4; ++r) {
            float v = rs[r];
            v += __shfl_xor(v, 1);
            v += __shfl_xor(v, 2);
            v += __shfl_xor(v, 4);
            v += __shfl_xor(v, 8);
            if ((lane & 15) == 0)
                eps[w * 64 + m * 16 + (lane >> 4) * 4 + r] = v;
        }
    }
    __syncthreads();
    partial[(size_t)y * N + tile_r + t] = eps[t];   // coalesced 256-float store
}

// ---------------- loss: reduce partials + per-row loss + single atomic per block ----------------
__global__ __launch_bounds__(256) void loss_part(const float* __restrict__ tgt,
                                                 const float* __restrict__ partial,
                                                 float* __restrict__ out) {
    int i = blockIdx.x * 256 + threadIdx.x;   // row
    float sum = 0.0f;
    #pragma unroll 1
    for (int y = 0; y < NY; ++y) sum += partial[(size_t)y * N + i];  // coalesced per y

    float tg = tgt[i];
    float num = S * (tg - MARGIN);
    float den = __expf(num) + sum - __expf(S * tg);
    float L = num - logf(den);

    float v = L;
    #pragma unroll
    for (int off = 1; off < 64; off <<= 1) v += __shfl_xor(v, off);
    __shared__ float s4[4];
    int lane = threadIdx.x & 63, w = threadIdx.x >> 6;
    if (lane == 0) s4[w] = v;
    __syncthreads();
    if (threadIdx.x == 0) {
        float bsum = s4[0] + s4[1] + s4[2] + s4[3];
        atomicAdd(out, -bsum / (float)N);
    }
}

// ---------------- launch ----------------
extern "C" void kernel_launch(void* const* d_in, const int* in_sizes, int n_in,
                              void* d_out, int out_size, void* d_ws, size_t ws_size,
                              hipStream_t stream) {
    const float* x = (const float*)d_in[0];
    const int* labels = (const int*)d_in[1];
    const float* W = (const float*)d_in[2];

    char* ws = (char*)d_ws;
    bf16* Af       = (bf16*)(ws);                    // N*D*2 (frag order)   =  8,388,608
    bf16* Wb       = (bf16*)(ws + 8388608);          // CP*D*2 (row-major)   =  5,177,344
    float* tgt     = (float*)(ws + 13565952);        // N*4                  =     65,536
    float* partial = (float*)(ws + 13631488);        // NY*N*4               =  5,177,344
    float* out = (float*)d_out;

    prep<<<PREPX_BLOCKS + PREPW_BLOCKS, 256, 0, stream>>>(x, labels, W, Af, tgt, Wb, out);
    gemm_exp<<<NWG, 256, 0, stream>>>(Af, Wb, partial);
    loss_part<<<N / 256, 256, 0, stream>>>(tgt, partial, out);
}

// Round 18
// 183.664 us; speedup vs baseline: 1.0726x; 1.0115x over previous
//
#include <hip/hip_runtime.h>
#include <hip/hip_bf16.h>
#include <math.h>

constexpr int N = 16384, D = 256, C = 10000;
constexpr float S = 30.0f, MARGIN = 0.4f;
constexpr int BM = 256, BN = 128;
constexpr int CP = ((C + BN - 1) / BN) * BN; // 10112
constexpr int NX = N / BM;                   // 64 row tiles
constexpr int NY = CP / BN;                  // 79 col tiles
constexpr int NWG = NX * NY;                 // 5056 = 8 * 8 * 79
constexpr float S_LOG2E = 43.2808512266689f; // S * log2(e)

constexpr int PREPX_BLOCKS = N / 16;          // 1024 (16-row groups, frag pack)
constexpr int PREPW_BLOCKS = CP / 16;         // 632  (16-col groups, frag pack)

using bf16 = __hip_bfloat16;
typedef __attribute__((ext_vector_type(8))) short short8;
typedef __attribute__((ext_vector_type(4))) float f32x4;

#define DRAIN_DMA()                                        \
    do {                                                   \
        asm volatile("s_waitcnt vmcnt(0)" ::: "memory");   \
        __builtin_amdgcn_sched_barrier(0);                 \
    } while (0)

__device__ inline short8 pack8(f32x4 a, f32x4 b, float sc) {
    short8 s;
    s[0] = (short)__bfloat16_as_ushort(__float2bfloat16(a.x * sc));
    s[1] = (short)__bfloat16_as_ushort(__float2bfloat16(a.y * sc));
    s[2] = (short)__bfloat16_as_ushort(__float2bfloat16(a.z * sc));
    s[3] = (short)__bfloat16_as_ushort(__float2bfloat16(a.w * sc));
    s[4] = (short)__bfloat16_as_ushort(__float2bfloat16(b.x * sc));
    s[5] = (short)__bfloat16_as_ushort(__float2bfloat16(b.y * sc));
    s[6] = (short)__bfloat16_as_ushort(__float2bfloat16(b.z * sc));
    s[7] = (short)__bfloat16_as_ushort(__float2bfloat16(b.w * sc));
    return s;
}

// ---------------- fused prep ----------------
// BOTH operands packed into 16x16x32 MFMA fragment order (R9-verified layout:
// frag (g16, kk) is 1 KB contiguous; lane l holds row/col g16*16+(l&15),
// k = kk*32 + (l>>4)*8 .. +8).
// x: normalize + pre-scale by S*log2e. W: plain convert, cols [C,CP) zeroed.
__global__ __launch_bounds__(256) void prep(const float* __restrict__ x,
                                            const int* __restrict__ labels,
                                            const float* __restrict__ W,
                                            bf16* __restrict__ Af,
                                            float* __restrict__ tgt,
                                            bf16* __restrict__ Bf,
                                            float* __restrict__ out) {
    const int bid = blockIdx.x;
    if (bid == 0 && threadIdx.x == 0) out[0] = 0.0f;

    const int tl = threadIdx.x;
    const int r = tl >> 4, c = tl & 15;

    if (bid < PREPX_BLOCKS) {
        const int rg = bid;
        const int row = rg * 16 + r;
        const float* xr = x + (size_t)row * D + c * 16;
        f32x4 v0 = *(const f32x4*)(xr + 0);
        f32x4 v1 = *(const f32x4*)(xr + 4);
        f32x4 v2 = *(const f32x4*)(xr + 8);
        f32x4 v3 = *(const f32x4*)(xr + 12);

        float ssq = v0.x*v0.x + v0.y*v0.y + v0.z*v0.z + v0.w*v0.w
                  + v1.x*v1.x + v1.y*v1.y + v1.z*v1.z + v1.w*v1.w
                  + v2.x*v2.x + v2.y*v2.y + v2.z*v2.z + v2.w*v2.w
                  + v3.x*v3.x + v3.y*v3.y + v3.z*v3.z + v3.w*v3.w;
        ssq += __shfl_xor(ssq, 1);
        ssq += __shfl_xor(ssq, 2);
        ssq += __shfl_xor(ssq, 4);
        ssq += __shfl_xor(ssq, 8);
        float rinv = rsqrtf(ssq);

        const int lab = labels[row];
        const float* wr = W + (size_t)lab * D + c * 16;
        f32x4 w0 = *(const f32x4*)(wr + 0);
        f32x4 w1 = *(const f32x4*)(wr + 4);
        f32x4 w2 = *(const f32x4*)(wr + 8);
        f32x4 w3 = *(const f32x4*)(wr + 12);
        float td = v0.x*w0.x + v0.y*w0.y + v0.z*w0.z + v0.w*w0.w
                 + v1.x*w1.x + v1.y*w1.y + v1.z*w1.z + v1.w*w1.w
                 + v2.x*w2.x + v2.y*w2.y + v2.z*w2.z + v2.w*w2.w
                 + v3.x*w3.x + v3.y*w3.y + v3.z*w3.z + v3.w*w3.w;
        td += __shfl_xor(td, 1);
        td += __shfl_xor(td, 2);
        td += __shfl_xor(td, 4);
        td += __shfl_xor(td, 8);
        if (c == 0) tgt[row] = td * rinv;

        const float sc = rinv * S_LOG2E;
        const size_t fb = ((size_t)rg * 8 + (c >> 1)) * 512;   // frag (rg, kk=c>>1)
        const int kq0 = (c & 1) * 2;
        *(short8*)(Af + fb + (size_t)(kq0 * 16 + r) * 8)       = pack8(v0, v1, sc);
        *(short8*)(Af + fb + (size_t)((kq0 + 1) * 16 + r) * 8) = pack8(v2, v3, sc);
    } else {
        const int rg = bid - PREPX_BLOCKS;     // 16-col group 0..631
        const int row = rg * 16 + r;           // class index
        f32x4 z = {0.f, 0.f, 0.f, 0.f};
        f32x4 v0 = z, v1 = z, v2 = z, v3 = z;
        if (row < C) {
            const float* wr = W + (size_t)row * D + c * 16;
            v0 = *(const f32x4*)(wr + 0);
            v1 = *(const f32x4*)(wr + 4);
            v2 = *(const f32x4*)(wr + 8);
            v3 = *(const f32x4*)(wr + 12);
        }
        const size_t fb = ((size_t)rg * 8 + (c >> 1)) * 512;
        const int kq0 = (c & 1) * 2;
        *(short8*)(Bf + fb + (size_t)(kq0 * 16 + r) * 8)       = pack8(v0, v1, 1.0f);
        *(short8*)(Bf + fb + (size_t)((kq0 + 1) * 16 + r) * 8) = pack8(v2, v3, 1.0f);
    }
}

// ---------------- main GEMM + exp2 + per-tile row partials ----------------
// R13 geometry (verified 105 us: 256 threads, 64 KB LDS, 2 blocks/CU) with
// the B path de-conflicted: Bf is ALREADY in fragment order in global, so
// the stage is a LINEAR 64 KB copy and every K-loop B-read is a contiguous
// 1 KB wave-read (Bs + frag*512 + lane*8, immediate offsets) — zero bank
// conflicts, no swizzle VALU. A frag-direct from L2, 1-deep ping-pong.
// Barrier-free K-loop; s_setprio(1) around the MFMA cluster (T5 regime:
// waves here are independent, not barrier-lockstep).
__global__ __launch_bounds__(256) void gemm_exp(const bf16* __restrict__ Af,
                                                const bf16* __restrict__ Bf,
                                                float* __restrict__ partial) { // [NY][N]
    __shared__ __align__(16) bf16 Bs[BN * D];   // 64 KB, fragment order

    // ---- XCD-aware decode (bijective: NWG = 8 * 8 * 79) ----
    const int bid = blockIdx.x;
    const int xcd = bid & 7;
    const int idx = bid >> 3;          // 0..631
    const int xl  = idx & 7;           // x within XCD chunk (fast)
    const int y   = idx >> 3;          // 0..78 (slow)
    const int tile_r = (xcd * 8 + xl) * BM;
    const int tile_c = y * BN;

    const int t = threadIdx.x;
    const int lane = t & 63, w = t >> 6;   // wave w owns rows w*64..+64, all 128 cols

    // ---- prologue: stage B panel = linear 64 KB copy (frag order preserved) ----
    // panel = frags [y*64, y*64+64) of Bf, 64 chunks of 1 KB
    #pragma unroll
    for (int q = 0; q < 16; ++q) {
        int cch = w * 16 + q;                     // chunk 0..63, wave-uniform
        const bf16* gb = Bf + ((size_t)y * 64 + cch) * 512 + lane * 8;
        __builtin_amdgcn_global_load_lds(
            (const __attribute__((address_space(1))) void*)gb,
            (__attribute__((address_space(3))) void*)(Bs + cch * 512),
            16, 0, 0);
    }

    // ---- A fragment pointers (frag-order buffer, contiguous 1KB per frag) ----
    const bf16* ap[4];
    #pragma unroll
    for (int m = 0; m < 4; ++m)
        ap[m] = Af + ((size_t)((tile_r >> 4) + w * 4 + m) * 8) * 512 + lane * 8;

    f32x4 acc[4][8] = {};
    short8 a[2][4];
    #pragma unroll
    for (int m = 0; m < 4; ++m) a[0][m] = *(const short8*)(ap[m]);  // overlaps DMA

    DRAIN_DMA();
    __syncthreads();   // B panel fully visible; the ONLY K-path barrier

    const bf16* bbase = Bs + lane * 8;   // all B reads: bbase + (n*8+kk)*512

    #pragma unroll
    for (int kk = 0; kk < 8; ++kk) {           // fully unrolled -> static indices
        const int cur = kk & 1, nxt = cur ^ 1;
        if (kk < 7) {
            #pragma unroll
            for (int m = 0; m < 4; ++m)
                a[nxt][m] = *(const short8*)(ap[m] + (kk + 1) * 512);
        }
        short8 bf[8];
        #pragma unroll
        for (int n = 0; n < 8; ++n)
            bf[n] = *(const short8*)(bbase + (n * 8 + kk) * 512);  // 1 KB contiguous/wave
        __builtin_amdgcn_s_setprio(1);
        #pragma unroll
        for (int m = 0; m < 4; ++m)
            #pragma unroll
            for (int n = 0; n < 8; ++n)
                acc[m][n] = __builtin_amdgcn_mfma_f32_16x16x32_bf16(a[cur][m], bf[n], acc[m][n], 0, 0, 0);
        __builtin_amdgcn_s_setprio(0);
    }

    __syncthreads();   // K-loop reads of Bs done; reuse as epilogue scratch
    float* eps = (float*)Bs;   // 256 floats

    // ---- epilogue: exp2(acc), mask padded cols, row sums (rows unique per wave) ----
    #pragma unroll
    for (int m = 0; m < 4; ++m) {
        float rs[4] = {0.f, 0.f, 0.f, 0.f};
        #pragma unroll
        for (int n = 0; n < 8; ++n) {
            int gcol = tile_c + n * 16 + (lane & 15);
            bool ok = (gcol < C);
            #pragma unroll
            for (int r = 0; r < 4; ++r) {
                float e = ok ? __builtin_amdgcn_exp2f(acc[m][n][r]) : 0.0f;
                rs[r] += e;
            }
        }
        #pragma unroll
        for (int r = 0; r < 4; ++r) {
            float v = rs[r];
            v += __shfl_xor(v, 1);
            v += __shfl_xor(v, 2);
            v += __shfl_xor(v, 4);
            v += __shfl_xor(v, 8);
            if ((lane & 15) == 0)
                eps[w * 64 + m * 16 + (lane >> 4) * 4 + r] = v;
        }
    }
    __syncthreads();
    partial[(size_t)y * N + tile_r + t] = eps[t];   // coalesced 256-float store
}

// ---------------- loss: reduce partials + per-row loss + single atomic per block ----------------
__global__ __launch_bounds__(256) void loss_part(const float* __restrict__ tgt,
                                                 const float* __restrict__ partial,
                                                 float* __restrict__ out) {
    int i = blockIdx.x * 256 + threadIdx.x;   // row
    float sum = 0.0f;
    #pragma unroll 1
    for (int y = 0; y < NY; ++y) sum += partial[(size_t)y * N + i];  // coalesced per y

    float tg = tgt[i];
    float num = S * (tg - MARGIN);
    float den = __expf(num) + sum - __expf(S * tg);
    float L = num - logf(den);

    float v = L;
    #pragma unroll
    for (int off = 1; off < 64; off <<= 1) v += __shfl_xor(v, off);
    __shared__ float s4[4];
    int lane = threadIdx.x & 63, w = threadIdx.x >> 6;
    if (lane == 0) s4[w] = v;
    __syncthreads();
    if (threadIdx.x == 0) {
        float bsum = s4[0] + s4[1] + s4[2] + s4[3];
        atomicAdd(out, -bsum / (float)N);
    }
}

// ---------------- launch ----------------
extern "C" void kernel_launch(void* const* d_in, const int* in_sizes, int n_in,
                              void* d_out, int out_size, void* d_ws, size_t ws_size,
                              hipStream_t stream) {
    const float* x = (const float*)d_in[0];
    const int* labels = (const int*)d_in[1];
    const float* W = (const float*)d_in[2];

    char* ws = (char*)d_ws;
    bf16* Af       = (bf16*)(ws);                    // N*D*2 (frag order)   =  8,388,608
    bf16* Bf       = (bf16*)(ws + 8388608);          // CP*D*2 (frag order)  =  5,177,344
    float* tgt     = (float*)(ws + 13565952);        // N*4                  =     65,536
    float* partial = (float*)(ws + 13631488);        // NY*N*4               =  5,177,344
    float* out = (float*)d_out;

    prep<<<PREPX_BLOCKS + PREPW_BLOCKS, 256, 0, stream>>>(x, labels, W, Af, tgt, Bf, out);
    gemm_exp<<<NWG, 256, 0, stream>>>(Af, Bf, partial);
    loss_part<<<N / 256, 256, 0, stream>>>(tgt, partial, out);
}

// Round 19
// 126.700 us; speedup vs baseline: 1.5549x; 1.4496x over previous
//
#include <hip/hip_runtime.h>
#include <hip/hip_bf16.h>
#include <math.h>

constexpr int N = 16384, D = 256, C = 10000;
constexpr float S = 30.0f, MARGIN = 0.4f;
constexpr int BM = 256, BN = 128;
constexpr int CP = ((C + BN - 1) / BN) * BN; // 10112
constexpr int NX = N / BM;                   // 64 row tiles
constexpr int NY = CP / BN;                  // 79 col tiles
constexpr int NWG = NX * NY;                 // 5056 = 8 * 8 * 79
constexpr float S_LOG2E = 43.2808512266689f; // S * log2(e)

constexpr int PREPX_BLOCKS = N / 16;          // 1024 (16-row groups, frag pack)
constexpr int PREPW_BLOCKS = (CP * D) / 1024; // 2528 (plain bf16 rows, padded)

using bf16 = __hip_bfloat16;
typedef __attribute__((ext_vector_type(8))) short short8;
typedef __attribute__((ext_vector_type(4))) short short4v;
typedef __attribute__((ext_vector_type(4))) float f32x4;

#define DRAIN_DMA()                                        \
    do {                                                   \
        asm volatile("s_waitcnt vmcnt(0)" ::: "memory");   \
        __builtin_amdgcn_sched_barrier(0);                 \
    } while (0)

__device__ inline short8 pack8(f32x4 a, f32x4 b, float sc) {
    short8 s;
    s[0] = (short)__bfloat16_as_ushort(__float2bfloat16(a.x * sc));
    s[1] = (short)__bfloat16_as_ushort(__float2bfloat16(a.y * sc));
    s[2] = (short)__bfloat16_as_ushort(__float2bfloat16(a.z * sc));
    s[3] = (short)__bfloat16_as_ushort(__float2bfloat16(a.w * sc));
    s[4] = (short)__bfloat16_as_ushort(__float2bfloat16(b.x * sc));
    s[5] = (short)__bfloat16_as_ushort(__float2bfloat16(b.y * sc));
    s[6] = (short)__bfloat16_as_ushort(__float2bfloat16(b.z * sc));
    s[7] = (short)__bfloat16_as_ushort(__float2bfloat16(b.w * sc));
    return s;
}

// ---------------- fused prep ----------------
// x: normalize + pre-scale by S*log2e, packed into 16x16x32 A-fragment order
//    (R9-verified). tgt in f32.
// W: plain row-major bf16, rows [C, CP) zero-padded — staged into LDS by the
//    GEMM via global_load_lds.
__global__ __launch_bounds__(256) void prep(const float* __restrict__ x,
                                            const int* __restrict__ labels,
                                            const float* __restrict__ W,
                                            bf16* __restrict__ Af,
                                            float* __restrict__ tgt,
                                            bf16* __restrict__ Wb,
                                            float* __restrict__ out) {
    const int bid = blockIdx.x;
    if (bid == 0 && threadIdx.x == 0) out[0] = 0.0f;

    if (bid < PREPX_BLOCKS) {
        const int tl = threadIdx.x;
        const int r = tl >> 4, c = tl & 15;
        const int rg = bid;
        const int row = rg * 16 + r;
        const float* xr = x + (size_t)row * D + c * 16;
        f32x4 v0 = *(const f32x4*)(xr + 0);
        f32x4 v1 = *(const f32x4*)(xr + 4);
        f32x4 v2 = *(const f32x4*)(xr + 8);
        f32x4 v3 = *(const f32x4*)(xr + 12);

        float ssq = v0.x*v0.x + v0.y*v0.y + v0.z*v0.z + v0.w*v0.w
                  + v1.x*v1.x + v1.y*v1.y + v1.z*v1.z + v1.w*v1.w
                  + v2.x*v2.x + v2.y*v2.y + v2.z*v2.z + v2.w*v2.w
                  + v3.x*v3.x + v3.y*v3.y + v3.z*v3.z + v3.w*v3.w;
        ssq += __shfl_xor(ssq, 1);
        ssq += __shfl_xor(ssq, 2);
        ssq += __shfl_xor(ssq, 4);
        ssq += __shfl_xor(ssq, 8);
        float rinv = rsqrtf(ssq);

        const int lab = labels[row];
        const float* wr = W + (size_t)lab * D + c * 16;
        f32x4 w0 = *(const f32x4*)(wr + 0);
        f32x4 w1 = *(const f32x4*)(wr + 4);
        f32x4 w2 = *(const f32x4*)(wr + 8);
        f32x4 w3 = *(const f32x4*)(wr + 12);
        float td = v0.x*w0.x + v0.y*w0.y + v0.z*w0.z + v0.w*w0.w
                 + v1.x*w1.x + v1.y*w1.y + v1.z*w1.z + v1.w*w1.w
                 + v2.x*w2.x + v2.y*w2.y + v2.z*w2.z + v2.w*w2.w
                 + v3.x*w3.x + v3.y*w3.y + v3.z*w3.z + v3.w*w3.w;
        td += __shfl_xor(td, 1);
        td += __shfl_xor(td, 2);
        td += __shfl_xor(td, 4);
        td += __shfl_xor(td, 8);
        if (c == 0) tgt[row] = td * rinv;

        const float sc = rinv * S_LOG2E;
        const size_t fb = ((size_t)rg * 8 + (c >> 1)) * 512;   // frag (rg, kk=c>>1)
        const int kq0 = (c & 1) * 2;
        *(short8*)(Af + fb + (size_t)(kq0 * 16 + r) * 8)       = pack8(v0, v1, sc);
        *(short8*)(Af + fb + (size_t)((kq0 + 1) * 16 + r) * 8) = pack8(v2, v3, sc);
    } else {
        // plain row-major W -> bf16, zero-pad rows [C, CP)
        int i = ((bid - PREPX_BLOCKS) * 256 + threadIdx.x) * 4;
        int r = i >> 8;                                  // D == 256
        short4v sv;
        if (r < C) {
            f32x4 v = *(const f32x4*)(W + i);
            sv.x = (short)__bfloat16_as_ushort(__float2bfloat16(v.x));
            sv.y = (short)__bfloat16_as_ushort(__float2bfloat16(v.y));
            sv.z = (short)__bfloat16_as_ushort(__float2bfloat16(v.z));
            sv.w = (short)__bfloat16_as_ushort(__float2bfloat16(v.w));
        } else {
            sv = short4v{0, 0, 0, 0};
        }
        *(short4v*)(Wb + i) = sv;
    }
}

// ---------------- main GEMM + exp2 + per-tile row partials ----------------
// R13 verified optimum (gemm 105.4 us): B panel [128 cols][K=256] staged ONCE
// into 64 KB LDS (XOR-swizzled, R8 stage geometry); A read frag-direct from
// L2 (R9 layout, 1-deep ping-pong). K-loop barrier-free. Per-wave tile 64x128.
// VGPR=124, 2 blocks/CU. Every single-variable mutation of this point
// (R14-R18: launch_bounds, 8-wave, 32KB LDS, 2-deep prefetch, setprio,
// frag-order B) measured SLOWER -> do not perturb.
__global__ __launch_bounds__(256, 2) void gemm_exp(const bf16* __restrict__ Af,
                                                   const bf16* __restrict__ Wb,
                                                   float* __restrict__ partial) { // [NY][N]
    __shared__ __align__(16) bf16 Bs[BN * D];   // 64 KB: [col][k], granule-swizzled

    // ---- XCD-aware decode (bijective: NWG = 8 * 8 * 79) ----
    const int bid = blockIdx.x;
    const int xcd = bid & 7;
    const int idx = bid >> 3;          // 0..631
    const int xl  = idx & 7;           // x within XCD chunk (fast)
    const int y   = idx >> 3;          // 0..78 (slow)
    const int tile_r = (xcd * 8 + xl) * BM;
    const int tile_c = y * BN;

    const int t = threadIdx.x;
    const int lane = t & 63, w = t >> 6;   // wave w owns rows w*64..+64, all 128 cols

    // ---- prologue: stage B panel (64 chunks of 1KB = 2 rows x 512B) ----
    #pragma unroll
    for (int q = 0; q < 16; ++q) {
        int c = w * 16 + q;                       // chunk 0..63, wave-uniform
        int row = 2 * c + (lane >> 5);            // B-panel row (= class col) 0..127
        int srcg = (lane & 31) ^ (row & 7);       // pre-swizzled source granule
        const bf16* gb = Wb + (size_t)(tile_c + row) * D + srcg * 8;
        __builtin_amdgcn_global_load_lds(
            (const __attribute__((address_space(1))) void*)gb,
            (__attribute__((address_space(3))) void*)(Bs + c * 512),
            16, 0, 0);
    }
    DRAIN_DMA();
    __syncthreads();   // B panel fully visible; the ONLY K-path barrier

    // ---- A fragment pointers (frag-order buffer, contiguous 1KB per frag) ----
    const bf16* ap[4];
    #pragma unroll
    for (int m = 0; m < 4; ++m)
        ap[m] = Af + ((size_t)((tile_r >> 4) + w * 4 + m) * 8) * 512 + lane * 8;

    f32x4 acc[4][8] = {};
    short8 a[2][4];
    #pragma unroll
    for (int m = 0; m < 4; ++m) a[0][m] = *(const short8*)(ap[m]);

    const int g0 = lane >> 4;       // k-quad within fragment
    const int x7 = lane & 7;        // swizzle key (row&7 == lane&7 for frag rows)

    #pragma unroll
    for (int kk = 0; kk < 8; ++kk) {           // fully unrolled -> static indices
        const int cur = kk & 1, nxt = cur ^ 1;
        if (kk < 7) {
            #pragma unroll
            for (int m = 0; m < 4; ++m)
                a[nxt][m] = *(const short8*)(ap[m] + (kk + 1) * 512);
        }
        short8 bf[8];
        #pragma unroll
        for (int n = 0; n < 8; ++n) {
            int row = n * 16 + (lane & 15);                 // B-panel row (class col)
            int g = (kk * 4 + g0) ^ x7;                     // swizzled k-granule
            bf[n] = *(const short8*)(Bs + row * 256 + g * 8);
        }
        #pragma unroll
        for (int m = 0; m < 4; ++m)
            #pragma unroll
            for (int n = 0; n < 8; ++n)
                acc[m][n] = __builtin_amdgcn_mfma_f32_16x16x32_bf16(a[cur][m], bf[n], acc[m][n], 0, 0, 0);
    }

    __syncthreads();   // K-loop reads of Bs done; reuse as epilogue scratch
    float* eps = (float*)Bs;   // 256 floats

    // ---- epilogue: exp2(acc), mask padded cols, row sums (rows unique per wave) ----
    #pragma unroll
    for (int m = 0; m < 4; ++m) {
        float rs[4] = {0.f, 0.f, 0.f, 0.f};
        #pragma unroll
        for (int n = 0; n < 8; ++n) {
            int gcol = tile_c + n * 16 + (lane & 15);
            bool ok = (gcol < C);
            #pragma unroll
            for (int r = 0; r < 4; ++r) {
                float e = ok ? __builtin_amdgcn_exp2f(acc[m][n][r]) : 0.0f;
                rs[r] += e;
            }
        }
        #pragma unroll
        for (int r = 0; r < 4; ++r) {
            float v = rs[r];
            v += __shfl_xor(v, 1);
            v += __shfl_xor(v, 2);
            v += __shfl_xor(v, 4);
            v += __shfl_xor(v, 8);
            if ((lane & 15) == 0)
                eps[w * 64 + m * 16 + (lane >> 4) * 4 + r] = v;
        }
    }
    __syncthreads();
    partial[(size_t)y * N + tile_r + t] = eps[t];   // coalesced 256-float store
}

// ---------------- loss: reduce partials + per-row loss + single atomic per block ----------------
__global__ __launch_bounds__(256) void loss_part(const float* __restrict__ tgt,
                                                 const float* __restrict__ partial,
                                                 float* __restrict__ out) {
    int i = blockIdx.x * 256 + threadIdx.x;   // row
    float sum = 0.0f;
    #pragma unroll 1
    for (int y = 0; y < NY; ++y) sum += partial[(size_t)y * N + i];  // coalesced per y

    float tg = tgt[i];
    float num = S * (tg - MARGIN);
    float den = __expf(num) + sum - __expf(S * tg);
    float L = num - logf(den);

    float v = L;
    #pragma unroll
    for (int off = 1; off < 64; off <<= 1) v += __shfl_xor(v, off);
    __shared__ float s4[4];
    int lane = threadIdx.x & 63, w = threadIdx.x >> 6;
    if (lane == 0) s4[w] = v;
    __syncthreads();
    if (threadIdx.x == 0) {
        float bsum = s4[0] + s4[1] + s4[2] + s4[3];
        atomicAdd(out, -bsum / (float)N);
    }
}

// ---------------- launch ----------------
extern "C" void kernel_launch(void* const* d_in, const int* in_sizes, int n_in,
                              void* d_out, int out_size, void* d_ws, size_t ws_size,
                              hipStream_t stream) {
    const float* x = (const float*)d_in[0];
    const int* labels = (const int*)d_in[1];
    const float* W = (const float*)d_in[2];

    char* ws = (char*)d_ws;
    bf16* Af       = (bf16*)(ws);                    // N*D*2 (frag order)   =  8,388,608
    bf16* Wb       = (bf16*)(ws + 8388608);          // CP*D*2 (row-major)   =  5,177,344
    float* tgt     = (float*)(ws + 13565952);        // N*4                  =     65,536
    float* partial = (float*)(ws + 13631488);        // NY*N*4               =  5,177,344
    float* out = (float*)d_out;

    prep<<<PREPX_BLOCKS + PREPW_BLOCKS, 256, 0, stream>>>(x, labels, W, Af, tgt, Wb, out);
    gemm_exp<<<NWG, 256, 0, stream>>>(Af, Wb, partial);
    loss_part<<<N / 256, 256, 0, stream>>>(tgt, partial, out);
}